// Round 7
// baseline (192.482 us; speedup 1.0000x reference)
//
#include <hip/hip_runtime.h>
#include <hip/hip_bf16.h>
#include <stdint.h>

// B=32, C=128->128, 56x56, 3x3 pad 1, two quantized branches fused as one
// conv with IC2=256.  R12: de-risked B-direct.  B operands bypass LDS --
// loaded global->VGPR from L2-resident wqb (294KB), double-buffered one step
// ahead.  A: double-buffered LDS (R7-proven sync skeleton: plain
// __syncthreads per step, no inline asm/raw barriers).  LDS 18 KB total.
#define BATCH 32
#define CH 128
#define HH 56
#define WW 56
#define HW 3136
#define M_TOTAL (BATCH*HW)
#define PLANE ((size_t)M_TOTAL * 16)   // bytes per 16B-chunk plane

using int4v   = __attribute__((ext_vector_type(4))) int;
using float4v = __attribute__((ext_vector_type(4))) float;

// ws layout (bytes):
//   wqb : i8  [9][128 oc][256 ic2] = 294,912  (B^T: ic contiguous)
//   scb : f32 sc_h[128], sc_l[128], bias[128] = 1,536
//   zp  : 256 B pattern page (bytes 0..127 = 0x80, 128..255 = 0x00)
//   aqn : i8  [16 planes][M_TOTAL pos][16 B] = 25,690,112
//         plane = branch*8 + cg  (high: planes 0-7, zp 0x80; low: 8-15, zp 0)
#define WQB_OFF 0
#define SCB_OFF 294912
#define ZP_OFF  296448
#define AQN_OFF 296704

#define GLD_LDS16(g, l)                                                        \
  __builtin_amdgcn_global_load_lds(                                            \
      (const __attribute__((address_space(1))) void*)(g),                      \
      (__attribute__((address_space(3))) void*)(l), 16, 0, 0)

#define KSTR 484   // per-channel LDS stride (floats): 8*60 + 4 pad

// ---------------- Kernel 1: fused prep (mask+act quant | weight quant) ------
// Blocks 0..1791: maskquant (b, 8-row band, 16-ch group).
// Blocks 1792..2047: per-OC weight quant -> int8 B^T + scales.
__global__ __launch_bounds__(256) void prep_kernel(
    const float* __restrict__ x,
    const float* __restrict__ wh, const float* __restrict__ wl,
    const float* __restrict__ p_sh, const float* __restrict__ p_sl,
    char* __restrict__ wqb, float* __restrict__ scb, int* __restrict__ zp,
    char* __restrict__ aqn) {
  __shared__ __align__(16) float smem[16 * KSTR + 128];  // 31.4 KB
  int t = threadIdx.x;

  if (blockIdx.x >= BATCH * 7 * 8) {
    // ---------------- weight-quant path ----------------
    int blk = blockIdx.x - BATCH * 7 * 8;
    int which = blk >> 7, oc = blk & 127;
    if (blk == 0 && t < 64)
      zp[t] = (t < 32) ? 0x80808080 : 0;  // pad pattern page
    const float* src = (which ? wl : wh) + (size_t)oc * 1152;
    float n = which ? 7.0f : 127.0f;  // signed narrow-range 2^(b-1)-1
    float* red = smem;
    int* ired = (int*)(smem + 256);

    float m = 0.0f;
    for (int e = t; e < 1152; e += 256) m = fmaxf(m, fabsf(src[e]));
    red[t] = m;
    __syncthreads();
    for (int s = 128; s > 0; s >>= 1) {
      if (t < s) red[t] = fmaxf(red[t], red[t + s]);
      __syncthreads();
    }
    float scale = red[0] / n;

    int partial = 0;
    for (int e = t; e < 1152; e += 256) {
      int tt = e >> 7, ic = e & 127;
      float q = rintf(src[ic * 9 + tt] / scale);  // jnp.round = RNE
      q = fminf(fmaxf(q, -n), n);
      int k = (int)q;
      partial += k;
      wqb[((size_t)tt * 128 + oc) * 256 + which * 128 + ic] = (char)k;
    }
    ired[t] = partial;
    __syncthreads();
    for (int s = 128; s > 0; s >>= 1) {
      if (t < s) ired[t] += ired[t + s];
      __syncthreads();
    }
    if (t == 0) {
      float s_act = which ? p_sl[0] : p_sh[0];
      float sc = s_act * scale;
      if (which == 0) {
        scb[oc] = sc;                                   // sc_h
        scb[256 + oc] = sc * 128.0f * (float)ired[0];   // offset-corr bias
      } else {
        scb[128 + oc] = sc;                             // sc_l
      }
    }
    return;
  }

  // ---------------- mask + act-quant path ----------------
  int bi = blockIdx.x;            // (b*7 + band)*8 + cg
  int cg = bi & 7;
  int bb = bi >> 3;
  int b = bb / 7, band = bb - b * 7;
  float* sx = smem;                       // [16][KSTR]
  float* smk = smem + 16 * KSTR;          // [16][7]
  #pragma unroll
  for (int i = 0; i < 7; ++i) {           // 1792 float4 = 16 k x 8 r x 14
    int idx = i * 256 + t;
    int k = idx / 112, rem = idx - k * 112;
    int r = rem / 14, w4 = rem - r * 14;
    *(float4v*)(sx + k * KSTR + r * 60 + w4 * 4) =
        *(const float4v*)(x + ((size_t)(b * 128 + cg * 16 + k)) * HW
                            + (band * 8 + r) * 56 + w4 * 4);
  }
  __syncthreads();
  if (t < 112) {                          // 16 k x 7 cells
    int k = t / 7, bw = t - (t / 7) * 7;
    float s = 0.0f;
    #pragma unroll
    for (int r = 0; r < 8; ++r)
      #pragma unroll
      for (int j = 0; j < 8; ++j)
        s += sx[k * KSTR + r * 60 + bw * 8 + j];
    smk[t] = (s * (1.0f / 64.0f) >= 0.05f) ? 1.0f : 0.0f;
  }
  __syncthreads();
  float shs = p_sh[0], sls = p_sl[0];
  #pragma unroll
  for (int it = 0; it < 2; ++it) {
    int pos = it * 256 + t;               // 448 = 8 r x 56 w
    if (pos < 448) {
      int r = pos / 56, w = pos - r * 56;
      int h = band * 8 + r;
      size_t gp = (size_t)b * HW + (size_t)h * 56 + w;   // position index
      int hw_[4] = {0, 0, 0, 0}, lw_[4] = {0, 0, 0, 0};
      int mcell = w >> 3;
      #pragma unroll
      for (int k = 0; k < 16; ++k) {
        float xv = sx[k * KSTR + r * 60 + w];
        bool mk = smk[k * 7 + mcell] != 0.0f;
        float xh = mk ? xv : 1e-5f;
        int kh = (int)fminf(fmaxf(rintf(xh / shs), 0.0f), 255.0f) - 128;
        float xl = mk ? 1e-5f : xv;
        int kl = (int)fminf(fmaxf(rintf(xl / sls), 0.0f), 15.0f);
        hw_[k >> 2] |= (kh & 0xff) << ((k & 3) * 8);
        lw_[k >> 2] |= (kl & 0xff) << ((k & 3) * 8);
      }
      *(int4v*)(aqn + ((size_t)cg * M_TOTAL + gp) * 16) =
          (int4v){hw_[0], hw_[1], hw_[2], hw_[3]};                 // high
      *(int4v*)(aqn + ((size_t)(8 + cg) * M_TOTAL + gp) * 16) =
          (int4v){lw_[0], lw_[1], lw_[2], lw_[3]};                 // low
    }
  }
}

// ---------------- Kernel 2: implicit-GEMM i8 MFMA conv ----------------------
// Grid (784 m-tiles XCD-chunked, 2 oc-halves).  Block 128m x 64oc, 4 waves of
// 64m x 32oc.  A: double-buffered LDS, 1-deep GLD_LDS prefetch, plain
// __syncthreads per step (R7-proven).  B: direct global->VGPR from
// L2-resident wqb, double-buffered 1 step ahead (no LDS, no staging).
__global__ __launch_bounds__(256, 3) void conv_mfma_kernel(
    const char* __restrict__ wqb,
    const char* __restrict__ aqn,
    const char* __restrict__ zp,
    const float* __restrict__ scb,
    float* __restrict__ out) {
  __shared__ __align__(16) char As[2][144 * 64];  // 2 x 9 KB (rows m0-8..+135)

  int tid = threadIdx.x;
  int lane = tid & 63, wv = tid >> 6;
  int wm = wv >> 1, wn = wv & 1;
  int lr = lane & 15, quad = lane >> 4;
  int bx = blockIdx.x;
  int m0 = (((bx & 7) * 98) + (bx >> 3)) * 128;   // bijective XCD chunking
  int oc0 = blockIdx.y * 64;

  // ---- A staging precompute: 9 groups of 16 rows; wave -> {wv, wv+4, wv+8}
  int ng = (wv == 0) ? 3 : 2;      // 9 groups: {0,4,8},{1,5},{2,6},{3,7}
  int sgrp[3] = {wv, wv + 4, wv + 8};
  const char* abase[3];
  const char* zbase[3];
  int avalid[3], ah[3];
  #pragma unroll
  for (int j = 0; j < 3; ++j) {
    int slot = sgrp[j] * 16 + (lane >> 2);
    int q = ((lane & 3) ^ (slot >> 1)) & 3;     // XOR-swizzled quarter/plane
    int p = m0 + slot - 8;                      // rows m0-8 .. m0+135
    int pv = (p >= 0) && (p < M_TOTAL);
    int pc = pv ? p : 0;
    int bb = pc / HW, rem = pc - bb * HW;
    int hh = rem / 56;
    abase[j] = aqn + (size_t)q * PLANE + (size_t)pc * 16;
    zbase[j] = zp + q * 16;
    avalid[j] = pv;
    ah[j] = hh;
  }
  // ---- B direct-load base: fragment (dwi,ni) at step (dh3,icc) =
  //      bq + ((dh3*3+dwi)*128 + ni*16)*256 + icc*64
  const char* bq = wqb + ((size_t)(oc0 + wn * 32 + lr)) * 256 + quad * 16;

  // ---- w-edge masks per m-fragment
  int lo_ok[4], hi_ok[4];
  #pragma unroll
  for (int mi = 0; mi < 4; ++mi) {
    int m = m0 + wm * 64 + mi * 16 + lr;
    int w = (m % HW) % 56;
    lo_ok[mi] = (w > 0);
    hi_ok[mi] = (w < 55);
  }

  int4v acch[4][2], accl[4][2];
  #pragma unroll
  for (int mi = 0; mi < 4; ++mi)
    #pragma unroll
    for (int ni = 0; ni < 2; ++ni) {
      acch[mi][ni] = (int4v){0, 0, 0, 0};
      accl[mi][ni] = (int4v){0, 0, 0, 0};
    }

  // stage A for step s (s = dh3*4 + icc) into buffer A
  auto stageA = [&](int s, char* A) {
    int dh3 = s >> 2, icc = s & 3;
    int dh = dh3 - 1;
    #pragma unroll
    for (int j = 0; j < 3; ++j) {
      if (j < ng) {
        int h2 = ah[j] + dh;
        bool ok = avalid[j] && ((unsigned)h2 < (unsigned)HH);
        const char* p = ok ? (abase[j] + dh * (56 * 16) + (size_t)icc * (4 * PLANE))
                           : (zbase[j] + icc * 64);
        GLD_LDS16(p, A + sgrp[j] * 1024);
      }
    }
  };
  // load B fragments for step s into registers (6 x dwordx4, L2-resident)
  auto loadB = [&](int s, int4v (&bf)[6]) {
    int dh3 = s >> 2, icc = s & 3;
    #pragma unroll
    for (int dwi = 0; dwi < 3; ++dwi)
      #pragma unroll
      for (int ni = 0; ni < 2; ++ni)
        bf[dwi * 2 + ni] = *(const int4v*)(
            bq + (size_t)(((dh3 * 3 + dwi) * 128 + ni * 16)) * 256 + icc * 64);
  };

  // compute step s from LDS A + register B
  auto compute = [&](int s, const char* A, const int4v (&bf6)[6]) {
    int icc = s & 3;
    const bool high = (icc < 2);
    const int patv = high ? (int)0x80808080 : 0;  // pad byte per branch
    const int4v pat = (int4v){patv, patv, patv, patv};
    #pragma unroll
    for (int dwi = 0; dwi < 3; ++dwi) {
      int4v af[4];
      #pragma unroll
      for (int mi = 0; mi < 4; ++mi) {
        int sA = wm * 64 + mi * 16 + lr + 7 + dwi;   // row base m0-8
        af[mi] = *(const int4v*)(A + sA * 64 + (((quad ^ (sA >> 1)) & 3) * 16));
        bool ok = (dwi == 1) | (dwi == 0 ? lo_ok[mi] : hi_ok[mi]);
        af[mi] = ok ? af[mi] : pat;
      }
      __builtin_amdgcn_s_setprio(1);
      if (high) {
        #pragma unroll
        for (int mi = 0; mi < 4; ++mi)
          #pragma unroll
          for (int ni = 0; ni < 2; ++ni)
            acch[mi][ni] = __builtin_amdgcn_mfma_i32_16x16x64_i8(
                af[mi], bf6[dwi * 2 + ni], acch[mi][ni], 0, 0, 0);
      } else {
        #pragma unroll
        for (int mi = 0; mi < 4; ++mi)
          #pragma unroll
          for (int ni = 0; ni < 2; ++ni)
            accl[mi][ni] = __builtin_amdgcn_mfma_i32_16x16x64_i8(
                af[mi], bf6[dwi * 2 + ni], accl[mi][ni], 0, 0, 0);
      }
      __builtin_amdgcn_s_setprio(0);
    }
  };

  // ---- pipeline (R7-proven skeleton): prefetch s+1 (B regs + A LDS),
  // compute s, one __syncthreads per step.  Buffer disjointness: compute
  // reads As[s&1]/bfr[s&1] while prefetch writes [s+1 & 1]; barrier protects
  // buffer reuse one iteration later.  Compiler inserts all data waits.
  int4v bfr[2][6];
  stageA(0, As[0]);
  loadB(0, bfr[0]);
  __syncthreads();
  #pragma unroll
  for (int s = 0; s < 12; ++s) {
    if (s < 11) {
      loadB(s + 1, bfr[(s + 1) & 1]);
      stageA(s + 1, As[(s + 1) & 1]);
    }
    compute(s, As[s & 1], bfr[s & 1]);
    __syncthreads();
  }

  // ---- Epilogue: y = sc_h*acc_h + sc_l*acc_l + bias, nt dwordx4 stores
  #pragma unroll
  for (int mi = 0; mi < 4; ++mi) {
    int m = m0 + wm * 64 + mi * 16 + quad * 4;
    int b = m / HW, r = m - b * HW;
    float* obase = out + (size_t)b * (CH * HW) + r;
    #pragma unroll
    for (int ni = 0; ni < 2; ++ni) {
      int oc = oc0 + wn * 32 + ni * 16 + lr;
      float sch = scb[oc], scl = scb[128 + oc], bs = scb[256 + oc];
      float4v f;
      #pragma unroll
      for (int rg = 0; rg < 4; ++rg)
        f[rg] = sch * (float)acch[mi][ni][rg] + scl * (float)accl[mi][ni][rg] + bs;
      __builtin_nontemporal_store(f, (float4v*)(obase + (size_t)oc * HW));
    }
  }
}

extern "C" void kernel_launch(void* const* d_in, const int* in_sizes, int n_in,
                              void* d_out, int out_size, void* d_ws, size_t ws_size,
                              hipStream_t stream) {
  const float* x  = (const float*)d_in[0];
  const float* wh = (const float*)d_in[1];
  const float* wl = (const float*)d_in[2];
  const float* sh = (const float*)d_in[3];
  const float* sl = (const float*)d_in[4];
  float* out = (float*)d_out;

  char* ws = (char*)d_ws;
  char* wqb  = ws + WQB_OFF;
  float* scb = (float*)(ws + SCB_OFF);
  int* zp    = (int*)(ws + ZP_OFF);
  char* aqn  = ws + AQN_OFF;

  prep_kernel<<<dim3(BATCH * 7 * 8 + 256), dim3(256), 0, stream>>>(
      x, wh, wl, sh, sl, wqb, scb, zp, aqn);
  conv_mfma_kernel<<<dim3(M_TOTAL / 128, 2), dim3(256), 0, stream>>>(
      wqb, aqn, (const char*)zp, scb, out);
}

// Round 8
// 164.424 us; speedup vs baseline: 1.1707x; 1.1707x over previous
//
#include <hip/hip_runtime.h>
#include <hip/hip_bf16.h>
#include <stdint.h>

// B=32, C=128->128, 56x56, 3x3 pad 1, two quantized branches fused as one
// conv with IC2=256.  R13: fat-wave conv.  Same 128m x 64oc block, same LDS
// (A 2x10KB + B 2x12KB = 44KB), same R7-verified sync skeleton -- but 2 waves
// of 64m x 64oc instead of 4 of 64x32: A-fragments amortize over 4 ni, LDS
// reads/MFMA drop 0.75 -> 0.5 (LDS pipe is the measured pole).
#define BATCH 32
#define CH 128
#define HH 56
#define WW 56
#define HW 3136
#define M_TOTAL (BATCH*HW)
#define PLANE ((size_t)M_TOTAL * 16)   // bytes per 16B-chunk plane

using int4v   = __attribute__((ext_vector_type(4))) int;
using float4v = __attribute__((ext_vector_type(4))) float;

// ws layout (bytes):
//   wqb : i8  [9][128 oc][256 ic2] = 294,912  (B^T: ic contiguous)
//   scb : f32 sc_h[128], sc_l[128], bias[128] = 1,536
//   zp  : 256 B pattern page (bytes 0..127 = 0x80, 128..255 = 0x00)
//   aqn : i8  [16 planes][M_TOTAL pos][16 B] = 25,690,112
//         plane = branch*8 + cg  (high: planes 0-7, zp 0x80; low: 8-15, zp 0)
#define WQB_OFF 0
#define SCB_OFF 294912
#define ZP_OFF  296448
#define AQN_OFF 296704

#define GLD_LDS16(g, l)                                                        \
  __builtin_amdgcn_global_load_lds(                                            \
      (const __attribute__((address_space(1))) void*)(g),                      \
      (__attribute__((address_space(3))) void*)(l), 16, 0, 0)

#define KSTR 484   // per-channel LDS stride (floats): 8*60 + 4 pad

// ---------------- Kernel 1: fused prep (mask+act quant | weight quant) ------
// Blocks 0..1791: maskquant (b, 8-row band, 16-ch group).
// Blocks 1792..2047: per-OC weight quant -> int8 B^T + scales.
__global__ __launch_bounds__(256) void prep_kernel(
    const float* __restrict__ x,
    const float* __restrict__ wh, const float* __restrict__ wl,
    const float* __restrict__ p_sh, const float* __restrict__ p_sl,
    char* __restrict__ wqb, float* __restrict__ scb, int* __restrict__ zp,
    char* __restrict__ aqn) {
  __shared__ __align__(16) float smem[16 * KSTR + 128];  // 31.4 KB
  int t = threadIdx.x;

  if (blockIdx.x >= BATCH * 7 * 8) {
    // ---------------- weight-quant path ----------------
    int blk = blockIdx.x - BATCH * 7 * 8;
    int which = blk >> 7, oc = blk & 127;
    if (blk == 0 && t < 64)
      zp[t] = (t < 32) ? 0x80808080 : 0;  // pad pattern page
    const float* src = (which ? wl : wh) + (size_t)oc * 1152;
    float n = which ? 7.0f : 127.0f;  // signed narrow-range 2^(b-1)-1
    float* red = smem;
    int* ired = (int*)(smem + 256);

    float m = 0.0f;
    for (int e = t; e < 1152; e += 256) m = fmaxf(m, fabsf(src[e]));
    red[t] = m;
    __syncthreads();
    for (int s = 128; s > 0; s >>= 1) {
      if (t < s) red[t] = fmaxf(red[t], red[t + s]);
      __syncthreads();
    }
    float scale = red[0] / n;

    int partial = 0;
    for (int e = t; e < 1152; e += 256) {
      int tt = e >> 7, ic = e & 127;
      float q = rintf(src[ic * 9 + tt] / scale);  // jnp.round = RNE
      q = fminf(fmaxf(q, -n), n);
      int k = (int)q;
      partial += k;
      wqb[((size_t)tt * 128 + oc) * 256 + which * 128 + ic] = (char)k;
    }
    ired[t] = partial;
    __syncthreads();
    for (int s = 128; s > 0; s >>= 1) {
      if (t < s) ired[t] += ired[t + s];
      __syncthreads();
    }
    if (t == 0) {
      float s_act = which ? p_sl[0] : p_sh[0];
      float sc = s_act * scale;
      if (which == 0) {
        scb[oc] = sc;                                   // sc_h
        scb[256 + oc] = sc * 128.0f * (float)ired[0];   // offset-corr bias
      } else {
        scb[128 + oc] = sc;                             // sc_l
      }
    }
    return;
  }

  // ---------------- mask + act-quant path ----------------
  int bi = blockIdx.x;            // (b*7 + band)*8 + cg
  int cg = bi & 7;
  int bb = bi >> 3;
  int b = bb / 7, band = bb - b * 7;
  float* sx = smem;                       // [16][KSTR]
  float* smk = smem + 16 * KSTR;          // [16][7]
  #pragma unroll
  for (int i = 0; i < 7; ++i) {           // 1792 float4 = 16 k x 8 r x 14
    int idx = i * 256 + t;
    int k = idx / 112, rem = idx - k * 112;
    int r = rem / 14, w4 = rem - r * 14;
    *(float4v*)(sx + k * KSTR + r * 60 + w4 * 4) =
        *(const float4v*)(x + ((size_t)(b * 128 + cg * 16 + k)) * HW
                            + (band * 8 + r) * 56 + w4 * 4);
  }
  __syncthreads();
  if (t < 112) {                          // 16 k x 7 cells
    int k = t / 7, bw = t - (t / 7) * 7;
    float s = 0.0f;
    #pragma unroll
    for (int r = 0; r < 8; ++r)
      #pragma unroll
      for (int j = 0; j < 8; ++j)
        s += sx[k * KSTR + r * 60 + bw * 8 + j];
    smk[t] = (s * (1.0f / 64.0f) >= 0.05f) ? 1.0f : 0.0f;
  }
  __syncthreads();
  float shs = p_sh[0], sls = p_sl[0];
  #pragma unroll
  for (int it = 0; it < 2; ++it) {
    int pos = it * 256 + t;               // 448 = 8 r x 56 w
    if (pos < 448) {
      int r = pos / 56, w = pos - r * 56;
      int h = band * 8 + r;
      size_t gp = (size_t)b * HW + (size_t)h * 56 + w;   // position index
      int hw_[4] = {0, 0, 0, 0}, lw_[4] = {0, 0, 0, 0};
      int mcell = w >> 3;
      #pragma unroll
      for (int k = 0; k < 16; ++k) {
        float xv = sx[k * KSTR + r * 60 + w];
        bool mk = smk[k * 7 + mcell] != 0.0f;
        float xh = mk ? xv : 1e-5f;
        int kh = (int)fminf(fmaxf(rintf(xh / shs), 0.0f), 255.0f) - 128;
        float xl = mk ? 1e-5f : xv;
        int kl = (int)fminf(fmaxf(rintf(xl / sls), 0.0f), 15.0f);
        hw_[k >> 2] |= (kh & 0xff) << ((k & 3) * 8);
        lw_[k >> 2] |= (kl & 0xff) << ((k & 3) * 8);
      }
      *(int4v*)(aqn + ((size_t)cg * M_TOTAL + gp) * 16) =
          (int4v){hw_[0], hw_[1], hw_[2], hw_[3]};                 // high
      *(int4v*)(aqn + ((size_t)(8 + cg) * M_TOTAL + gp) * 16) =
          (int4v){lw_[0], lw_[1], lw_[2], lw_[3]};                 // low
    }
  }
}

// ---------------- Kernel 2: implicit-GEMM i8 MFMA conv ----------------------
// Grid (784 m-tiles XCD-chunked, 2 oc-halves).  Block 128m x 64oc, 2 waves of
// 64m x 64oc (fat waves: A-frags amortize over 4 ni).  A 2x10KB + B 2x12KB
// LDS double-buffered, 1-deep GLD_LDS prefetch, __syncthreads per step.
__global__ __launch_bounds__(128, 2) void conv_mfma_kernel(
    const char* __restrict__ wqb,
    const char* __restrict__ aqn,
    const char* __restrict__ zp,
    const float* __restrict__ scb,
    float* __restrict__ out) {
  __shared__ __align__(16) char As[2][160 * 64];  // 2 x 10 KB (16-row halo)
  __shared__ __align__(16) char Bs[2][192 * 64];  // 2 x 12 KB (3 taps x 64 oc)

  int tid = threadIdx.x;
  int lane = tid & 63, wv = tid >> 6;              // wv in {0,1} = m-half
  int lr = lane & 15, quad = lane >> 4;
  int bx = blockIdx.x;
  int m0 = (((bx & 7) * 98) + (bx >> 3)) * 128;   // bijective XCD chunking
  int oc0 = blockIdx.y * 64;

  // ---- A staging precompute: 10 groups of 16 rows; wave w -> {w+2j, j<5}
  int sgrp[5];
  const char* abase[5];
  const char* zbase[5];
  int avalid[5], ah[5];
  #pragma unroll
  for (int j = 0; j < 5; ++j) {
    sgrp[j] = wv + 2 * j;
    int slot = sgrp[j] * 16 + (lane >> 2);
    int q = ((lane & 3) ^ (slot >> 1)) & 3;     // XOR-swizzled quarter/plane
    int p = m0 + slot - 16;                     // rows m0-16 .. m0+143
    int pv = (p >= 0) && (p < M_TOTAL);
    int pc = pv ? p : 0;
    int bb = pc / HW, rem = pc - bb * HW;
    int hh = rem / 56;
    abase[j] = aqn + (size_t)q * PLANE + (size_t)pc * 16;
    zbase[j] = zp + q * 16;
    avalid[j] = pv;
    ah[j] = hh;
  }
  // ---- B staging precompute: 6 groups of 16 rows per wave (192 total)
  const char* bbase[6];
  #pragma unroll
  for (int i = 0; i < 6; ++i) {
    int slot = (wv * 6 + i) * 16 + (lane >> 2);      // [dwi 3][ocr 64]
    int qp = (((lane & 3) ^ (slot >> 1)) & 3) * 16;
    int dwi_s = slot >> 6, ocr = slot & 63;
    bbase[i] = wqb + ((size_t)(dwi_s * 128 + oc0 + ocr)) * 256 + qp;
  }
  // ---- w-edge masks per m-fragment
  int lo_ok[4], hi_ok[4];
  #pragma unroll
  for (int mi = 0; mi < 4; ++mi) {
    int m = m0 + wv * 64 + mi * 16 + lr;
    int w = (m % HW) % 56;
    lo_ok[mi] = (w > 0);
    hi_ok[mi] = (w < 55);
  }

  int4v acch[4][4], accl[4][4];
  #pragma unroll
  for (int mi = 0; mi < 4; ++mi)
    #pragma unroll
    for (int ni = 0; ni < 4; ++ni) {
      acch[mi][ni] = (int4v){0, 0, 0, 0};
      accl[mi][ni] = (int4v){0, 0, 0, 0};
    }

  // stage A for step s (s = dh3*4 + icc) into buffer A
  auto stageA = [&](int s, char* A) {
    int dh3 = s >> 2, icc = s & 3;
    int dh = dh3 - 1;
    #pragma unroll
    for (int j = 0; j < 5; ++j) {
      int h2 = ah[j] + dh;
      bool ok = avalid[j] && ((unsigned)h2 < (unsigned)HH);
      const char* p = ok ? (abase[j] + dh * (56 * 16) + (size_t)icc * (4 * PLANE))
                         : (zbase[j] + icc * 64);
      GLD_LDS16(p, A + sgrp[j] * 1024);
    }
  };
  // stage B for step s into buffer B
  auto stageB = [&](int s, char* B) {
    int dh3 = s >> 2, icc = s & 3;
    #pragma unroll
    for (int i = 0; i < 6; ++i)
      GLD_LDS16(bbase[i] + (size_t)dh3 * 98304 + icc * 64,
                B + ((wv * 6 + i) * 16) * 64);
  };

  // compute step s from buffers A,B: per dwi, 4 af + 4 bf reads -> 16 MFMA
  auto compute = [&](int s, const char* A, const char* B) {
    int icc = s & 3;
    const bool high = (icc < 2);
    const int patv = high ? (int)0x80808080 : 0;  // pad byte per branch
    const int4v pat = (int4v){patv, patv, patv, patv};
    #pragma unroll
    for (int dwi = 0; dwi < 3; ++dwi) {
      int4v af[4], bf[4];
      #pragma unroll
      for (int mi = 0; mi < 4; ++mi) {
        int sA = wv * 64 + mi * 16 + lr + 15 + dwi;
        af[mi] = *(const int4v*)(A + sA * 64 + (((quad ^ (sA >> 1)) & 3) * 16));
        bool ok = (dwi == 1) | (dwi == 0 ? lo_ok[mi] : hi_ok[mi]);
        af[mi] = ok ? af[mi] : pat;
      }
      #pragma unroll
      for (int ni = 0; ni < 4; ++ni) {
        int sB = dwi * 64 + ni * 16 + lr;
        bf[ni] = *(const int4v*)(B + sB * 64 + (((quad ^ (sB >> 1)) & 3) * 16));
      }
      __builtin_amdgcn_s_setprio(1);
      if (high) {
        #pragma unroll
        for (int mi = 0; mi < 4; ++mi)
          #pragma unroll
          for (int ni = 0; ni < 4; ++ni)
            acch[mi][ni] = __builtin_amdgcn_mfma_i32_16x16x64_i8(
                af[mi], bf[ni], acch[mi][ni], 0, 0, 0);
      } else {
        #pragma unroll
        for (int mi = 0; mi < 4; ++mi)
          #pragma unroll
          for (int ni = 0; ni < 4; ++ni)
            accl[mi][ni] = __builtin_amdgcn_mfma_i32_16x16x64_i8(
                af[mi], bf[ni], accl[mi][ni], 0, 0, 0);
      }
      __builtin_amdgcn_s_setprio(0);
    }
  };

  // ---- pipeline (R7-proven skeleton): prefetch s+1, compute s, one
  // __syncthreads per step.
  stageA(0, As[0]);
  stageB(0, Bs[0]);
  __syncthreads();
  #pragma unroll
  for (int s = 0; s < 12; ++s) {
    if (s < 11) {
      stageB(s + 1, Bs[(s + 1) & 1]);
      stageA(s + 1, As[(s + 1) & 1]);
    }
    compute(s, As[s & 1], Bs[s & 1]);
    __syncthreads();
  }

  // ---- Epilogue: y = sc_h*acc_h + sc_l*acc_l + bias, dwordx4 stores
  #pragma unroll
  for (int mi = 0; mi < 4; ++mi) {
    int m = m0 + wv * 64 + mi * 16 + quad * 4;
    int b = m / HW, r = m - b * HW;
    float* obase = out + (size_t)b * (CH * HW) + r;
    #pragma unroll
    for (int ni = 0; ni < 4; ++ni) {
      int oc = oc0 + ni * 16 + lr;
      float sch = scb[oc], scl = scb[128 + oc], bs = scb[256 + oc];
      float4v f;
      #pragma unroll
      for (int rg = 0; rg < 4; ++rg)
        f[rg] = sch * (float)acch[mi][ni][rg] + scl * (float)accl[mi][ni][rg] + bs;
      *(float4v*)(obase + (size_t)oc * HW) = f;
    }
  }
}

extern "C" void kernel_launch(void* const* d_in, const int* in_sizes, int n_in,
                              void* d_out, int out_size, void* d_ws, size_t ws_size,
                              hipStream_t stream) {
  const float* x  = (const float*)d_in[0];
  const float* wh = (const float*)d_in[1];
  const float* wl = (const float*)d_in[2];
  const float* sh = (const float*)d_in[3];
  const float* sl = (const float*)d_in[4];
  float* out = (float*)d_out;

  char* ws = (char*)d_ws;
  char* wqb  = ws + WQB_OFF;
  float* scb = (float*)(ws + SCB_OFF);
  int* zp    = (int*)(ws + ZP_OFF);
  char* aqn  = ws + AQN_OFF;

  prep_kernel<<<dim3(BATCH * 7 * 8 + 256), dim3(256), 0, stream>>>(
      x, wh, wl, sh, sl, wqb, scb, zp, aqn);
  conv_mfma_kernel<<<dim3(M_TOTAL / 128, 2), dim3(128), 0, stream>>>(
      wqb, aqn, (const char*)zp, scb, out);
}

// Round 9
// 151.977 us; speedup vs baseline: 1.2665x; 1.0819x over previous
//
#include <hip/hip_runtime.h>
#include <hip/hip_bf16.h>
#include <stdint.h>

// B=32, C=128->128, 56x56, 3x3 pad 1, two quantized branches fused as one
// conv with IC2=256.  R14: occupancy play.  One 128m x 128oc block (8 waves
// of the R2-proven 64m x 32oc wave tile) replaces the two oc-half blocks:
// B staged once for 128 oc, A fetched once per m-tile, LDS 68 KB -> 2
// blocks/CU = 16 waves/CU (2.2x the measured TLP of R2).  Plain stores
// (R13 evidence: nt-stores inflated WRITE 71->50 MB).  R7 sync skeleton.
#define BATCH 32
#define CH 128
#define HH 56
#define WW 56
#define HW 3136
#define M_TOTAL (BATCH*HW)
#define PLANE ((size_t)M_TOTAL * 16)   // bytes per 16B-chunk plane

using int4v   = __attribute__((ext_vector_type(4))) int;
using float4v = __attribute__((ext_vector_type(4))) float;

// ws layout (bytes):
//   wqb : i8  [9][128 oc][256 ic2] = 294,912  (B^T: ic contiguous)
//   scb : f32 sc_h[128], sc_l[128], bias[128] = 1,536
//   zp  : 256 B pattern page (bytes 0..127 = 0x80, 128..255 = 0x00)
//   aqn : i8  [16 planes][M_TOTAL pos][16 B] = 25,690,112
//         plane = branch*8 + cg  (high: planes 0-7, zp 0x80; low: 8-15, zp 0)
#define WQB_OFF 0
#define SCB_OFF 294912
#define ZP_OFF  296448
#define AQN_OFF 296704

#define GLD_LDS16(g, l)                                                        \
  __builtin_amdgcn_global_load_lds(                                            \
      (const __attribute__((address_space(1))) void*)(g),                      \
      (__attribute__((address_space(3))) void*)(l), 16, 0, 0)

#define KSTR 484   // per-channel LDS stride (floats): 8*60 + 4 pad

// ---------------- Kernel 1: fused prep (mask+act quant | weight quant) ------
// Blocks 0..1791: maskquant (b, 8-row band, 16-ch group).
// Blocks 1792..2047: per-OC weight quant -> int8 B^T + scales.
__global__ __launch_bounds__(256) void prep_kernel(
    const float* __restrict__ x,
    const float* __restrict__ wh, const float* __restrict__ wl,
    const float* __restrict__ p_sh, const float* __restrict__ p_sl,
    char* __restrict__ wqb, float* __restrict__ scb, int* __restrict__ zp,
    char* __restrict__ aqn) {
  __shared__ __align__(16) float smem[16 * KSTR + 128];  // 31.4 KB
  int t = threadIdx.x;

  if (blockIdx.x >= BATCH * 7 * 8) {
    // ---------------- weight-quant path ----------------
    int blk = blockIdx.x - BATCH * 7 * 8;
    int which = blk >> 7, oc = blk & 127;
    if (blk == 0 && t < 64)
      zp[t] = (t < 32) ? 0x80808080 : 0;  // pad pattern page
    const float* src = (which ? wl : wh) + (size_t)oc * 1152;
    float n = which ? 7.0f : 127.0f;  // signed narrow-range 2^(b-1)-1
    float* red = smem;
    int* ired = (int*)(smem + 256);

    float m = 0.0f;
    for (int e = t; e < 1152; e += 256) m = fmaxf(m, fabsf(src[e]));
    red[t] = m;
    __syncthreads();
    for (int s = 128; s > 0; s >>= 1) {
      if (t < s) red[t] = fmaxf(red[t], red[t + s]);
      __syncthreads();
    }
    float scale = red[0] / n;

    int partial = 0;
    for (int e = t; e < 1152; e += 256) {
      int tt = e >> 7, ic = e & 127;
      float q = rintf(src[ic * 9 + tt] / scale);  // jnp.round = RNE
      q = fminf(fmaxf(q, -n), n);
      int k = (int)q;
      partial += k;
      wqb[((size_t)tt * 128 + oc) * 256 + which * 128 + ic] = (char)k;
    }
    ired[t] = partial;
    __syncthreads();
    for (int s = 128; s > 0; s >>= 1) {
      if (t < s) ired[t] += ired[t + s];
      __syncthreads();
    }
    if (t == 0) {
      float s_act = which ? p_sl[0] : p_sh[0];
      float sc = s_act * scale;
      if (which == 0) {
        scb[oc] = sc;                                   // sc_h
        scb[256 + oc] = sc * 128.0f * (float)ired[0];   // offset-corr bias
      } else {
        scb[128 + oc] = sc;                             // sc_l
      }
    }
    return;
  }

  // ---------------- mask + act-quant path ----------------
  int bi = blockIdx.x;            // (b*7 + band)*8 + cg
  int cg = bi & 7;
  int bb = bi >> 3;
  int b = bb / 7, band = bb - b * 7;
  float* sx = smem;                       // [16][KSTR]
  float* smk = smem + 16 * KSTR;          // [16][7]
  #pragma unroll
  for (int i = 0; i < 7; ++i) {           // 1792 float4 = 16 k x 8 r x 14
    int idx = i * 256 + t;
    int k = idx / 112, rem = idx - k * 112;
    int r = rem / 14, w4 = rem - r * 14;
    *(float4v*)(sx + k * KSTR + r * 60 + w4 * 4) =
        *(const float4v*)(x + ((size_t)(b * 128 + cg * 16 + k)) * HW
                            + (band * 8 + r) * 56 + w4 * 4);
  }
  __syncthreads();
  if (t < 112) {                          // 16 k x 7 cells
    int k = t / 7, bw = t - (t / 7) * 7;
    float s = 0.0f;
    #pragma unroll
    for (int r = 0; r < 8; ++r)
      #pragma unroll
      for (int j = 0; j < 8; ++j)
        s += sx[k * KSTR + r * 60 + bw * 8 + j];
    smk[t] = (s * (1.0f / 64.0f) >= 0.05f) ? 1.0f : 0.0f;
  }
  __syncthreads();
  float shs = p_sh[0], sls = p_sl[0];
  #pragma unroll
  for (int it = 0; it < 2; ++it) {
    int pos = it * 256 + t;               // 448 = 8 r x 56 w
    if (pos < 448) {
      int r = pos / 56, w = pos - r * 56;
      int h = band * 8 + r;
      size_t gp = (size_t)b * HW + (size_t)h * 56 + w;   // position index
      int hw_[4] = {0, 0, 0, 0}, lw_[4] = {0, 0, 0, 0};
      int mcell = w >> 3;
      #pragma unroll
      for (int k = 0; k < 16; ++k) {
        float xv = sx[k * KSTR + r * 60 + w];
        bool mk = smk[k * 7 + mcell] != 0.0f;
        float xh = mk ? xv : 1e-5f;
        int kh = (int)fminf(fmaxf(rintf(xh / shs), 0.0f), 255.0f) - 128;
        float xl = mk ? 1e-5f : xv;
        int kl = (int)fminf(fmaxf(rintf(xl / sls), 0.0f), 15.0f);
        hw_[k >> 2] |= (kh & 0xff) << ((k & 3) * 8);
        lw_[k >> 2] |= (kl & 0xff) << ((k & 3) * 8);
      }
      *(int4v*)(aqn + ((size_t)cg * M_TOTAL + gp) * 16) =
          (int4v){hw_[0], hw_[1], hw_[2], hw_[3]};                 // high
      *(int4v*)(aqn + ((size_t)(8 + cg) * M_TOTAL + gp) * 16) =
          (int4v){lw_[0], lw_[1], lw_[2], lw_[3]};                 // low
    }
  }
}

// ---------------- Kernel 2: implicit-GEMM i8 MFMA conv ----------------------
// Grid: 784 m-tiles (XCD-chunked), one block per tile.  Block 128m x 128oc,
// 8 waves (2 wm x 4 wn) of 64m x 32oc each (R2-proven wave tile).  A 2x10KB,
// B 2x24KB (3 taps x 128 oc) double-buffered; 1-deep GLD_LDS prefetch;
// __syncthreads per step.  68 KB LDS -> 2 blocks/CU = 16 waves/CU.
__global__ __launch_bounds__(512, 4) void conv_mfma_kernel(
    const char* __restrict__ wqb,
    const char* __restrict__ aqn,
    const char* __restrict__ zp,
    const float* __restrict__ scb,
    float* __restrict__ out) {
  __shared__ __align__(16) char As[2][160 * 64];  // 2 x 10 KB (16-row halo)
  __shared__ __align__(16) char Bs[2][384 * 64];  // 2 x 24 KB (3 taps x 128 oc)

  int tid = threadIdx.x;
  int lane = tid & 63, wv = tid >> 6;              // 8 waves
  int wm = wv >> 2, wn = wv & 3;                   // 2 m-halves x 4 oc-quarters
  int lr = lane & 15, quad = lane >> 4;
  int bx = blockIdx.x;
  int m0 = (((bx & 7) * 98) + (bx >> 3)) * 128;   // bijective XCD chunking

  // ---- A staging: 10 groups of 16 rows; waves 0-7 take groups 0-7,
  //      waves 0,1 also take groups 8,9.
  int ng = (wv < 2) ? 2 : 1;
  int sgrp[2] = {wv, wv + 8};
  const char* abase[2];
  const char* zbase[2];
  int avalid[2], ah[2];
  #pragma unroll
  for (int j = 0; j < 2; ++j) {
    int slot = sgrp[j] * 16 + (lane >> 2);
    int q = ((lane & 3) ^ (slot >> 1)) & 3;     // XOR-swizzled quarter/plane
    int p = m0 + slot - 16;                     // rows m0-16 .. m0+143
    int pv = (p >= 0) && (p < M_TOTAL);
    int pc = pv ? p : 0;
    int bb = pc / HW, rem = pc - bb * HW;
    int hh = rem / 56;
    abase[j] = aqn + (size_t)q * PLANE + (size_t)pc * 16;
    zbase[j] = zp + q * 16;
    avalid[j] = pv;
    ah[j] = hh;
  }
  // ---- B staging: 24 groups of 16 rows (384 rows = [dwi 3][ocr 128]);
  //      wave w takes groups w*3 .. w*3+2.
  const char* bbase[3];
  #pragma unroll
  for (int i = 0; i < 3; ++i) {
    int slot = (wv * 3 + i) * 16 + (lane >> 2);      // 0..383
    int qp = (((lane & 3) ^ (slot >> 1)) & 3) * 16;
    int dwi_s = slot >> 7, ocr = slot & 127;
    bbase[i] = wqb + ((size_t)(dwi_s * 128 + ocr)) * 256 + qp;
  }
  // ---- w-edge masks per m-fragment
  int lo_ok[4], hi_ok[4];
  #pragma unroll
  for (int mi = 0; mi < 4; ++mi) {
    int m = m0 + wm * 64 + mi * 16 + lr;
    int w = (m % HW) % 56;
    lo_ok[mi] = (w > 0);
    hi_ok[mi] = (w < 55);
  }

  int4v acch[4][2], accl[4][2];
  #pragma unroll
  for (int mi = 0; mi < 4; ++mi)
    #pragma unroll
    for (int ni = 0; ni < 2; ++ni) {
      acch[mi][ni] = (int4v){0, 0, 0, 0};
      accl[mi][ni] = (int4v){0, 0, 0, 0};
    }

  // stage A for step s (s = dh3*4 + icc) into buffer A
  auto stageA = [&](int s, char* A) {
    int dh3 = s >> 2, icc = s & 3;
    int dh = dh3 - 1;
    #pragma unroll
    for (int j = 0; j < 2; ++j) {
      if (j < ng) {
        int h2 = ah[j] + dh;
        bool ok = avalid[j] && ((unsigned)h2 < (unsigned)HH);
        const char* p = ok ? (abase[j] + dh * (56 * 16) + (size_t)icc * (4 * PLANE))
                           : (zbase[j] + icc * 64);
        GLD_LDS16(p, A + sgrp[j] * 1024);
      }
    }
  };
  // stage B for step s into buffer B (3 groups per wave)
  auto stageB = [&](int s, char* B) {
    int dh3 = s >> 2, icc = s & 3;
    #pragma unroll
    for (int i = 0; i < 3; ++i)
      GLD_LDS16(bbase[i] + (size_t)dh3 * 98304 + icc * 64,
                B + ((wv * 3 + i) * 16) * 64);
  };

  // compute step s from buffers A,B
  auto compute = [&](int s, const char* A, const char* B) {
    int icc = s & 3;
    const bool high = (icc < 2);
    const int patv = high ? (int)0x80808080 : 0;  // pad byte per branch
    const int4v pat = (int4v){patv, patv, patv, patv};
    #pragma unroll
    for (int dwi = 0; dwi < 3; ++dwi) {
      int4v af[4], bf[2];
      #pragma unroll
      for (int mi = 0; mi < 4; ++mi) {
        int sA = wm * 64 + mi * 16 + lr + 15 + dwi;
        af[mi] = *(const int4v*)(A + sA * 64 + (((quad ^ (sA >> 1)) & 3) * 16));
        bool ok = (dwi == 1) | (dwi == 0 ? lo_ok[mi] : hi_ok[mi]);
        af[mi] = ok ? af[mi] : pat;
      }
      #pragma unroll
      for (int ni = 0; ni < 2; ++ni) {
        int sB = dwi * 128 + wn * 32 + ni * 16 + lr;
        bf[ni] = *(const int4v*)(B + sB * 64 + (((quad ^ (sB >> 1)) & 3) * 16));
      }
      __builtin_amdgcn_s_setprio(1);
      if (high) {
        #pragma unroll
        for (int mi = 0; mi < 4; ++mi)
          #pragma unroll
          for (int ni = 0; ni < 2; ++ni)
            acch[mi][ni] = __builtin_amdgcn_mfma_i32_16x16x64_i8(
                af[mi], bf[ni], acch[mi][ni], 0, 0, 0);
      } else {
        #pragma unroll
        for (int mi = 0; mi < 4; ++mi)
          #pragma unroll
          for (int ni = 0; ni < 2; ++ni)
            accl[mi][ni] = __builtin_amdgcn_mfma_i32_16x16x64_i8(
                af[mi], bf[ni], accl[mi][ni], 0, 0, 0);
      }
      __builtin_amdgcn_s_setprio(0);
    }
  };

  // ---- pipeline (R7-proven skeleton): prefetch s+1, compute s, one
  // __syncthreads per step.
  stageA(0, As[0]);
  stageB(0, Bs[0]);
  __syncthreads();
  #pragma unroll
  for (int s = 0; s < 12; ++s) {
    if (s < 11) {
      stageB(s + 1, Bs[(s + 1) & 1]);
      stageA(s + 1, As[(s + 1) & 1]);
    }
    compute(s, As[s & 1], Bs[s & 1]);
    __syncthreads();
  }

  // ---- Epilogue: y = sc_h*acc_h + sc_l*acc_l + bias, plain dwordx4 stores
  // (full 64B lines per wave: 4 quads x 4 consecutive m per lane-group).
  #pragma unroll
  for (int mi = 0; mi < 4; ++mi) {
    int m = m0 + wm * 64 + mi * 16 + quad * 4;
    int b = m / HW, r = m - b * HW;
    float* obase = out + (size_t)b * (CH * HW) + r;
    #pragma unroll
    for (int ni = 0; ni < 2; ++ni) {
      int oc = wn * 32 + ni * 16 + lr;
      float sch = scb[oc], scl = scb[128 + oc], bs = scb[256 + oc];
      float4v f;
      #pragma unroll
      for (int rg = 0; rg < 4; ++rg)
        f[rg] = sch * (float)acch[mi][ni][rg] + scl * (float)accl[mi][ni][rg] + bs;
      *(float4v*)(obase + (size_t)oc * HW) = f;
    }
  }
}

extern "C" void kernel_launch(void* const* d_in, const int* in_sizes, int n_in,
                              void* d_out, int out_size, void* d_ws, size_t ws_size,
                              hipStream_t stream) {
  const float* x  = (const float*)d_in[0];
  const float* wh = (const float*)d_in[1];
  const float* wl = (const float*)d_in[2];
  const float* sh = (const float*)d_in[3];
  const float* sl = (const float*)d_in[4];
  float* out = (float*)d_out;

  char* ws = (char*)d_ws;
  char* wqb  = ws + WQB_OFF;
  float* scb = (float*)(ws + SCB_OFF);
  int* zp    = (int*)(ws + ZP_OFF);
  char* aqn  = ws + AQN_OFF;

  prep_kernel<<<dim3(BATCH * 7 * 8 + 256), dim3(256), 0, stream>>>(
      x, wh, wl, sh, sl, wqb, scb, zp, aqn);
  conv_mfma_kernel<<<dim3(M_TOTAL / 128), dim3(512), 0, stream>>>(
      wqb, aqn, (const char*)zp, scb, out);
}